// Round 1
// baseline (31.048 us; speedup 1.0000x reference)
//
#include <hip/hip_runtime.h>

// VQC: 8 qubits, 2 layers, B=4096. One wave (64 lanes) per batch element.
// Amplitude index a in [0,256): a = (lane<<2) | r, r in 0..3.
// Qubit w corresponds to bit b = 7-w of a.
//   b in {0,1}  -> in-thread amp bits (r)
//   b in {2..7} -> lane bit (b-2)

__device__ __forceinline__ float shfx(float v, int m) {
    return __shfl_xor(v, m, 64);
}

__global__ __launch_bounds__(256) void vqc_kernel(
    const float* __restrict__ x,      // [4096,8]
    const float* __restrict__ prm,    // [104]
    const float* __restrict__ W,      // [10,8]
    const float* __restrict__ bvec,   // [10]
    float* __restrict__ out)          // [4096,10]
{
    const int lane = threadIdx.x & 63;
    const int bi   = (blockIdx.x << 2) + (threadIdx.x >> 6);

    float re[4], im[4];

    // ---- initial product state: RY(x_w * pi) applied to |0...0>
    float cw[8], swv[8];
    #pragma unroll
    for (int w = 0; w < 8; ++w) {
        float ang = x[bi * 8 + w] * 1.57079632679489662f; // x*pi/2
        __sincosf(ang, &swv[w], &cw[w]);
    }
    float base = 1.0f;
    #pragma unroll
    for (int w = 0; w < 6; ++w)
        base *= ((lane >> (5 - w)) & 1) ? swv[w] : cw[w];
    re[0] = base * cw[6]  * cw[7];
    re[1] = base * cw[6]  * swv[7];
    re[2] = base * swv[6] * cw[7];
    re[3] = base * swv[6] * swv[7];
    im[0] = im[1] = im[2] = im[3] = 0.0f;

    // ---- gate helpers (bb is compile-time after full unroll) ----
    auto rx_pair = [&](int i0, int i1, float c, float s) {
        float r0 = c*re[i0] + s*im[i1];
        float m0 = c*im[i0] - s*re[i1];
        float r1 = c*re[i1] + s*im[i0];
        float m1 = c*im[i1] - s*re[i0];
        re[i0]=r0; im[i0]=m0; re[i1]=r1; im[i1]=m1;
    };
    auto ry_pair = [&](int i0, int i1, float c, float s) {
        float r0 = c*re[i0] - s*re[i1];
        float m0 = c*im[i0] - s*im[i1];
        float r1 = s*re[i0] + c*re[i1];
        float m1 = s*im[i0] + c*im[i1];
        re[i0]=r0; im[i0]=m0; re[i1]=r1; im[i1]=m1;
    };
    auto apply_rx = [&](int bb, float c, float s) {
        if (bb >= 2) {
            int mk = 1 << (bb - 2);
            // RX symmetric (u00=u11=c, u01=u10=-is): same formula both sides
            #pragma unroll
            for (int r = 0; r < 4; ++r) {
                float pre = shfx(re[r], mk), pim = shfx(im[r], mk);
                float nr = c*re[r] + s*pim;
                float ni = c*im[r] - s*pre;
                re[r]=nr; im[r]=ni;
            }
        } else if (bb == 1) { rx_pair(0,2,c,s); rx_pair(1,3,c,s); }
        else                { rx_pair(0,1,c,s); rx_pair(2,3,c,s); }
    };
    auto apply_ry = [&](int bb, float c, float s) {
        if (bb >= 2) {
            int mk = 1 << (bb - 2);
            float sg = ((lane >> (bb - 2)) & 1) ? s : -s;
            #pragma unroll
            for (int r = 0; r < 4; ++r) {
                float pre = shfx(re[r], mk), pim = shfx(im[r], mk);
                re[r] = c*re[r] + sg*pre;
                im[r] = c*im[r] + sg*pim;
            }
        } else if (bb == 1) { ry_pair(0,2,c,s); ry_pair(1,3,c,s); }
        else                { ry_pair(0,1,c,s); ry_pair(2,3,c,s); }
    };
    auto apply_rz = [&](int bb, float c, float s) {
        if (bb >= 2) {
            float sg = ((lane >> (bb - 2)) & 1) ? s : -s;
            #pragma unroll
            for (int r = 0; r < 4; ++r) {
                float nr = c*re[r] - sg*im[r];
                float ni = c*im[r] + sg*re[r];
                re[r]=nr; im[r]=ni;
            }
        } else {
            #pragma unroll
            for (int r = 0; r < 4; ++r) {
                float sg = ((r >> bb) & 1) ? s : -s;
                float nr = c*re[r] - sg*im[r];
                float ni = c*im[r] + sg*re[r];
                re[r]=nr; im[r]=ni;
            }
        }
    };
    // CNOT(control bit bc, target bit bt) followed by RZ(theta) on target.
    // Always bc > bt (since i < j -> 7-i > 7-j).
    auto cnot_rz = [&](int bc, int bt, float c, float s) {
        if (bt >= 2) {
            int  tmk = 1 << (bt - 2);
            bool cb  = (lane >> (bc - 2)) & 1;   // bc > bt >= 2 -> lane bit
            #pragma unroll
            for (int r = 0; r < 4; ++r) {
                float pre = shfx(re[r], tmk), pim = shfx(im[r], tmk);
                re[r] = cb ? pre : re[r];
                im[r] = cb ? pim : im[r];
            }
        } else if (bt == 1) {
            bool cb = (lane >> (bc - 2)) & 1;    // bc >= 2
            float r0=re[0], r1=re[1], r2=re[2], r3=re[3];
            float m0=im[0], m1=im[1], m2=im[2], m3=im[3];
            re[0] = cb ? r2 : r0;  re[2] = cb ? r0 : r2;
            re[1] = cb ? r3 : r1;  re[3] = cb ? r1 : r3;
            im[0] = cb ? m2 : m0;  im[2] = cb ? m0 : m2;
            im[1] = cb ? m3 : m1;  im[3] = cb ? m1 : m3;
        } else { // bt == 0
            if (bc >= 2) {
                bool cb = (lane >> (bc - 2)) & 1;
                float r0=re[0], r1=re[1], r2=re[2], r3=re[3];
                float m0=im[0], m1=im[1], m2=im[2], m3=im[3];
                re[0] = cb ? r1 : r0;  re[1] = cb ? r0 : r1;
                re[2] = cb ? r3 : r2;  re[3] = cb ? r2 : r3;
                im[0] = cb ? m1 : m0;  im[1] = cb ? m0 : m1;
                im[2] = cb ? m3 : m2;  im[3] = cb ? m2 : m3;
            } else { // bc == 1: control = r bit1, target = r bit0: swap amps 2,3
                float t;
                t=re[2]; re[2]=re[3]; re[3]=t;
                t=im[2]; im[2]=im[3]; im[3]=t;
            }
        }
        apply_rz(bt, c, s);
    };

    // ---- 2 variational layers ----
    #pragma unroll
    for (int l = 0; l < 2; ++l) {
        const int base0 = l * 52;
        #pragma unroll
        for (int i = 0; i < 8; ++i) {
            float c, s;
            __sincosf(prm[base0 + 3*i    ] * 0.5f, &s, &c);
            apply_rx(7 - i, c, s);
            __sincosf(prm[base0 + 3*i + 1] * 0.5f, &s, &c);
            apply_ry(7 - i, c, s);
            __sincosf(prm[base0 + 3*i + 2] * 0.5f, &s, &c);
            apply_rz(7 - i, c, s);
        }
        int k = 0;
        #pragma unroll
        for (int i = 0; i < 8; ++i) {
            #pragma unroll
            for (int j = i + 1; j < 8; ++j) {
                float c, s;
                __sincosf(prm[base0 + 24 + k] * 0.5f, &s, &c);
                cnot_rz(7 - i, 7 - j, c, s);
                ++k;
            }
        }
    }

    // ---- expectation values <Z_w> ----
    float p0 = re[0]*re[0] + im[0]*im[0];
    float p1 = re[1]*re[1] + im[1]*im[1];
    float p2 = re[2]*re[2] + im[2]*im[2];
    float p3 = re[3]*re[3] + im[3]*im[3];
    float psum = p0 + p1 + p2 + p3;

    float ev[8];
    #pragma unroll
    for (int w = 0; w < 6; ++w)
        ev[w] = ((lane >> (5 - w)) & 1) ? -psum : psum;
    ev[6] = p0 + p1 - p2 - p3;
    ev[7] = p0 - p1 + p2 - p3;

    #pragma unroll
    for (int w = 0; w < 8; ++w) {
        #pragma unroll
        for (int m = 1; m < 64; m <<= 1)
            ev[w] += shfx(ev[w], m);
    }

    // ---- linear head: out[bi,c] = sum_w ev[w]*W[c,w] + b[c]
    if (lane < 10) {
        float acc = bvec[lane];
        #pragma unroll
        for (int w = 0; w < 8; ++w)
            acc += ev[w] * W[lane * 8 + w];
        out[bi * 10 + lane] = acc;
    }
}

extern "C" void kernel_launch(void* const* d_in, const int* in_sizes, int n_in,
                              void* d_out, int out_size, void* d_ws, size_t ws_size,
                              hipStream_t stream) {
    const float* x    = (const float*)d_in[0];   // [4096,8]
    const float* prm  = (const float*)d_in[1];   // [104]
    const float* W    = (const float*)d_in[2];   // [10,8]
    const float* bvec = (const float*)d_in[3];   // [10]
    float* out = (float*)d_out;                  // [4096,10]

    const int B = in_sizes[0] / 8;               // 4096
    const int blocks = B / 4;                    // 4 waves (batch elems) per block
    vqc_kernel<<<blocks, 256, 0, stream>>>(x, prm, W, bvec, out);
}

// Round 2
// 17.644 us; speedup vs baseline: 1.7597x; 1.7597x over previous
//
#include <hip/hip_runtime.h>

// VQC 8 qubits / 2 layers / B=4096. One wave per batch element.
// Amplitude index a in [0,256): a = (lane<<2)|r. Qubit q <-> bit (7-q).
//   bits 2..7 -> lane bits 0..5 ; bits 0..1 -> in-thread regs r.
//
// Per layer: 8 fused SU(2) rotations (RZ*RY*RX precomputed), then the whole
// CNOT+RZ entanglement block collapses to:
//   |a> -> e^{i phi_l(a)} |a ^ (a>>1)>       (Gray-code permutation)
// with phi_l(a) = sum_k (+-) theta_k/2, sign from a_i ^ a_j of ORIGINAL bits.
// Pre-kernel builds the 16 fused matrices and the 2x256 (cos,sin) phase tables.

#define PI_HALF 1.57079632679489662f

__device__ __forceinline__ float shfx(float v, int m)      { return __shfl_xor(v, m, 64); }
__device__ __forceinline__ float shfl_from(float v, int l) { return __shfl(v, l, 64); }

// ---------------- pre-kernel: params -> ws tables ----------------
// ws layout (floats): [0..63]  rot: l*32 + q*4 + {ar,ai,br,bi}
//                     [64..1087] phase: (l*256 + a)*2 + {cos,sin}
__global__ __launch_bounds__(640) void vqc_pre(
    const float* __restrict__ prm, float* __restrict__ ws)
{
    const int t = threadIdx.x;
    if (t < 512) {
        const int l = t >> 8, a = t & 255;
        float phi = 0.f;
        int k = 0;
        #pragma unroll
        for (int i = 0; i < 8; ++i)
            #pragma unroll
            for (int j = i + 1; j < 8; ++j, ++k) {
                float th = prm[l * 52 + 24 + k];
                int bit = ((a >> (7 - i)) ^ (a >> (7 - j))) & 1;
                phi += bit ? 0.5f * th : -0.5f * th;
            }
        float c, s;
        __sincosf(phi, &s, &c);
        ws[64 + (l * 256 + a) * 2 + 0] = c;
        ws[64 + (l * 256 + a) * 2 + 1] = s;
    } else if (t < 528) {
        const int idx = t - 512;
        const int l = idx >> 3, q = idx & 7;
        float cx, sx, cy, sy, cz, sz;
        __sincosf(prm[l * 52 + 3 * q    ] * 0.5f, &sx, &cx);
        __sincosf(prm[l * 52 + 3 * q + 1] * 0.5f, &sy, &cy);
        __sincosf(prm[l * 52 + 3 * q + 2] * 0.5f, &sz, &cz);
        // M = RZ * RY * RX ; alpha = M00, beta = M01 ; M = [[a,b],[-conj(b),conj(a)]]
        // N = RY*RX: N00 = cy*cx + i*sy*sx ; N01 = -sy*cx - i*cy*sx ; e = cz - i*sz
        float n00r =  cy * cx, n00i =  sy * sx;
        float n01r = -sy * cx, n01i = -cy * sx;
        ws[l * 32 + q * 4 + 0] = cz * n00r + sz * n00i;   // ar
        ws[l * 32 + q * 4 + 1] = cz * n00i - sz * n00r;   // ai
        ws[l * 32 + q * 4 + 2] = cz * n01r + sz * n01i;   // br
        ws[l * 32 + q * 4 + 3] = cz * n01i - sz * n01r;   // bi
    }
}

// ---------------- main kernel ----------------
__global__ __launch_bounds__(256) void vqc_main(
    const float* __restrict__ x,      // [4096,8]
    const float* __restrict__ ws,     // tables from vqc_pre
    const float* __restrict__ W,      // [10,8]
    const float* __restrict__ bvec,   // [10]
    float* __restrict__ out)          // [4096,10]
{
    const int lane = threadIdx.x & 63;
    const int bi = __builtin_amdgcn_readfirstlane((blockIdx.x << 2) + (threadIdx.x >> 6));

    // ---- initial product state: RY(x_w*pi)|0..0>
    float cw[8], swv[8];
    #pragma unroll
    for (int w = 0; w < 8; ++w) {
        float ang = x[bi * 8 + w] * PI_HALF;
        __sincosf(ang, &swv[w], &cw[w]);
    }
    float base = 1.f;
    #pragma unroll
    for (int w = 0; w < 6; ++w)
        base *= ((lane >> (5 - w)) & 1) ? swv[w] : cw[w];
    float re[4], im[4];
    re[0] = base * cw[6]  * cw[7];  re[1] = base * cw[6]  * swv[7];
    re[2] = base * swv[6] * cw[7];  re[3] = base * swv[6] * swv[7];
    im[0] = im[1] = im[2] = im[3] = 0.f;

    // ---- permutation constants (Gray decode = suffix-xor)
    const int pr = __popc(lane) & 1;            // parity of target lane bits
    int g = lane; g ^= g >> 1; g ^= g >> 2; g ^= g >> 4;
    const int src_lane = g;                     // source lane for gather

    #pragma unroll
    for (int l = 0; l < 2; ++l) {
        // ---- 8 fused rotations (qubit i -> amplitude bit p = 7-i)
        #pragma unroll
        for (int i = 0; i < 8; ++i) {
            const float ar  = ws[l * 32 + i * 4 + 0];
            const float ai  = ws[l * 32 + i * 4 + 1];
            const float br  = ws[l * 32 + i * 4 + 2];
            const float bi_ = ws[l * 32 + i * 4 + 3];
            const int p = 7 - i;
            if (p >= 2) {
                const int mk = 1 << (p - 2);
                const int h  = (lane >> (p - 2)) & 1;
                const float Ai = h ? -ai : ai;
                const float Br = h ? -br : br;
                #pragma unroll
                for (int r = 0; r < 4; ++r) {
                    float pre = shfx(re[r], mk), pim = shfx(im[r], mk);
                    float cr = re[r], ci = im[r];
                    re[r] = ar * cr - Ai * ci + Br * pre - bi_ * pim;
                    im[r] = ar * ci + Ai * cr + Br * pim + bi_ * pre;
                }
            } else if (p == 1) {
                #pragma unroll
                for (int r0i = 0; r0i < 2; ++r0i) {      // pairs (0,2),(1,3)
                    const int i0 = r0i, i1 = r0i + 2;
                    float r0 = re[i0], i0v = im[i0], r1 = re[i1], i1v = im[i1];
                    re[i0] =  ar * r0 - ai * i0v + br * r1 - bi_ * i1v;
                    im[i0] =  ar * i0v + ai * r0 + br * i1v + bi_ * r1;
                    re[i1] = -br * r0 - bi_ * i0v + ar * r1 + ai * i1v;
                    im[i1] = -br * i0v + bi_ * r0 + ar * i1v - ai * r1;
                }
            } else {
                #pragma unroll
                for (int r0i = 0; r0i < 2; ++r0i) {      // pairs (0,1),(2,3)
                    const int i0 = 2 * r0i, i1 = 2 * r0i + 1;
                    float r0 = re[i0], i0v = im[i0], r1 = re[i1], i1v = im[i1];
                    re[i0] =  ar * r0 - ai * i0v + br * r1 - bi_ * i1v;
                    im[i0] =  ar * i0v + ai * r0 + br * i1v + bi_ * r1;
                    re[i1] = -br * r0 - bi_ * i0v + ar * r1 + ai * i1v;
                    im[i1] = -br * i0v + bi_ * r0 + ar * i1v - ai * r1;
                }
            }
        }

        // ---- diagonal phase e^{i phi_l(a)} at pre-permutation index
        const float4* ph = (const float4*)(ws + 64 + l * 512);
        float4 f0 = ph[lane * 2], f1 = ph[lane * 2 + 1];
        {
            float nr, ni;
            nr = f0.x * re[0] - f0.y * im[0]; ni = f0.x * im[0] + f0.y * re[0]; re[0] = nr; im[0] = ni;
            nr = f0.z * re[1] - f0.w * im[1]; ni = f0.z * im[1] + f0.w * re[1]; re[1] = nr; im[1] = ni;
            nr = f1.x * re[2] - f1.y * im[2]; ni = f1.x * im[2] + f1.y * re[2]; re[2] = nr; im[2] = ni;
            nr = f1.z * re[3] - f1.w * im[3]; ni = f1.z * im[3] + f1.w * re[3]; re[3] = nr; im[3] = ni;
        }

        // ---- Gray permutation: new[b] = old[P^-1 b], P(a)=a^(a>>1)
        float Bre[4], Bim[4];
        #pragma unroll
        for (int m = 0; m < 4; ++m) {
            Bre[m] = shfl_from(re[m], src_lane);
            Bim[m] = shfl_from(im[m], src_lane);
        }
        // src_reg map: pr=0 -> {0,1,3,2}, pr=1 -> {3,2,0,1}
        re[0] = pr ? Bre[3] : Bre[0];  im[0] = pr ? Bim[3] : Bim[0];
        re[1] = pr ? Bre[2] : Bre[1];  im[1] = pr ? Bim[2] : Bim[1];
        re[2] = pr ? Bre[0] : Bre[3];  im[2] = pr ? Bim[0] : Bim[3];
        re[3] = pr ? Bre[1] : Bre[2];  im[3] = pr ? Bim[1] : Bim[2];
    }

    // ---- measurement
    float p0 = re[0]*re[0] + im[0]*im[0];
    float p1 = re[1]*re[1] + im[1]*im[1];
    float p2 = re[2]*re[2] + im[2]*im[2];
    float p3 = re[3]*re[3] + im[3]*im[3];
    float psum = p0 + p1 + p2 + p3;

    // 6-stage WHT butterfly: lane h ends with sum_l (-1)^popc(h&l) psum[l]
    float v = psum;
    #pragma unroll
    for (int m = 1; m < 64; m <<= 1) {
        float pp = shfx(v, m);
        v = (lane & m) ? (pp - v) : (v + pp);
    }
    // full sums for the two in-thread qubits
    float q6 = p0 + p1 - p2 - p3;
    float q7 = p0 - p1 + p2 - p3;
    #pragma unroll
    for (int m = 1; m < 64; m <<= 1) { q6 += shfx(q6, m); q7 += shfx(q7, m); }

    // ev[w] (w=0..5) sits at lane 1<<(5-w); broadcast to all lanes
    float e0 = shfl_from(v, 32), e1 = shfl_from(v, 16), e2 = shfl_from(v, 8);
    float e3 = shfl_from(v, 4),  e4 = shfl_from(v, 2),  e5 = shfl_from(v, 1);

    // ---- linear head
    if (lane < 10) {
        const float* Wr = W + lane * 8;
        float acc = bvec[lane];
        acc += e0 * Wr[0] + e1 * Wr[1] + e2 * Wr[2] + e3 * Wr[3];
        acc += e4 * Wr[4] + e5 * Wr[5] + q6 * Wr[6] + q7 * Wr[7];
        out[bi * 10 + lane] = acc;
    }
}

extern "C" void kernel_launch(void* const* d_in, const int* in_sizes, int n_in,
                              void* d_out, int out_size, void* d_ws, size_t ws_size,
                              hipStream_t stream) {
    const float* x    = (const float*)d_in[0];   // [4096,8]
    const float* prm  = (const float*)d_in[1];   // [104]
    const float* W    = (const float*)d_in[2];   // [10,8]
    const float* bvec = (const float*)d_in[3];   // [10]
    float* out = (float*)d_out;                  // [4096,10]
    float* ws  = (float*)d_ws;                   // 4352 B used

    vqc_pre<<<1, 640, 0, stream>>>(prm, ws);

    const int B = in_sizes[0] / 8;               // 4096
    vqc_main<<<B / 4, 256, 0, stream>>>(x, ws, W, bvec, out);
}

// Round 3
// 14.190 us; speedup vs baseline: 2.1881x; 1.2435x over previous
//
#include <hip/hip_runtime.h>

// VQC 8 qubits / 2 layers / B=4096 — single fused kernel, one wave per batch elem.
// Amplitude a = (lane<<2)|r ; qubit q <-> bit (7-q); bits>=2 are lane bits.
//
// Per layer: 8 fused SU(2) rotations (matrices computed by lanes 0..15, read via
// readlane), then CNOT+RZ block = diagonal phase e^{i*phi(a)} x Gray permutation
// a -> a^(a>>1). phi computed in-register from the Ising form:
//   phi = 0.5*(A +- B6 +- B7 +- T), signs from amplitude bits of qubits 6,7.
// Layer-2 permutation is NOT applied; measurement reads WHT coefficients at
// remapped masks instead (P is GF(2)-linear).

#define PI_HALF 1.57079632679489662f

__device__ __forceinline__ float shfx(float v, int m)      { return __shfl_xor(v, m, 64); }
__device__ __forceinline__ float shfl_from(float v, int l) { return __shfl(v, l, 64); }
__device__ __forceinline__ float rdlane(float v, int l) {
    return __int_as_float(__builtin_amdgcn_readlane(__float_as_int(v), l));
}
// +th if (pword&1)==1 else -th   (3 VALU: shl, xor, then consumer add)
__device__ __forceinline__ float sgnterm(float th, int pword) {
    return __int_as_float(__float_as_int(-th) ^ (int)((unsigned)pword << 31));
}

__global__ __launch_bounds__(256) void vqc_fused(
    const float* __restrict__ x,      // [4096,8]
    const float* __restrict__ prm,    // [104]
    const float* __restrict__ W,      // [10,8]
    const float* __restrict__ bvec,   // [10]
    float* __restrict__ out)          // [4096,10]
{
    const int lane = threadIdx.x & 63;
    const int bi = __builtin_amdgcn_readfirstlane((blockIdx.x << 2) + (threadIdx.x >> 6));

    // ---- distributed fused-rotation matrices: lane t in [0,16) owns (l=t>>3, q=t&7)
    float mar, mai, mbr, mbi;
    {
        const int t = lane & 15;
        const int l = t >> 3, q = t & 7;
        const float* p3 = prm + l * 52 + 3 * q;
        float cx, sx, cy, sy, cz, sz;
        __sincosf(p3[0] * 0.5f, &sx, &cx);
        __sincosf(p3[1] * 0.5f, &sy, &cy);
        __sincosf(p3[2] * 0.5f, &sz, &cz);
        float n00r =  cy * cx, n00i =  sy * sx;
        float n01r = -sy * cx, n01i = -cy * sx;
        mar = cz * n00r + sz * n00i;
        mai = cz * n00i - sz * n00r;
        mbr = cz * n01r + sz * n01i;
        mbi = cz * n01i - sz * n01r;
    }

    // ---- initial product state: RY(x_w*pi)|0..0>
    float cw[8], swv[8];
    {
        const float4 x0 = ((const float4*)(x + bi * 8))[0];
        const float4 x1 = ((const float4*)(x + bi * 8))[1];
        float xv[8] = {x0.x, x0.y, x0.z, x0.w, x1.x, x1.y, x1.z, x1.w};
        #pragma unroll
        for (int w = 0; w < 8; ++w)
            __sincosf(xv[w] * PI_HALF, &swv[w], &cw[w]);
    }
    float base = 1.f;
    #pragma unroll
    for (int w = 0; w < 6; ++w)
        base *= ((lane >> (5 - w)) & 1) ? swv[w] : cw[w];
    float re[4], im[4];
    re[0] = base * cw[6]  * cw[7];  re[1] = base * cw[6]  * swv[7];
    re[2] = base * swv[6] * cw[7];  re[3] = base * swv[6] * swv[7];
    im[0] = im[1] = im[2] = im[3] = 0.f;

    // ---- per-lane bit words for phase signs
    int lb[6];
    #pragma unroll
    for (int b = 0; b < 6; ++b) lb[b] = lane >> b;

    // ---- Gray permutation constants (layer 1 only)
    const int pr = __popc(lane) & 1;
    int g = lane; g ^= g >> 1; g ^= g >> 2; g ^= g >> 4;
    const int src_lane = g;

    #pragma unroll
    for (int l = 0; l < 2; ++l) {
        // ---- 8 fused rotations (qubit i -> amplitude bit p = 7-i)
        #pragma unroll
        for (int i = 0; i < 8; ++i) {
            const int srcl = l * 8 + i;
            const float ar  = rdlane(mar, srcl);
            const float ai  = rdlane(mai, srcl);
            const float br  = rdlane(mbr, srcl);
            const float bi_ = rdlane(mbi, srcl);
            const int p = 7 - i;
            if (p >= 2) {
                const int mk = 1 << (p - 2);
                const int h  = (lane >> (p - 2)) & 1;
                const float Ai = h ? -ai : ai;
                const float Br = h ? -br : br;
                #pragma unroll
                for (int r = 0; r < 4; ++r) {
                    float pre = shfx(re[r], mk), pim = shfx(im[r], mk);
                    float cr = re[r], ci = im[r];
                    re[r] = ar * cr - Ai * ci + Br * pre - bi_ * pim;
                    im[r] = ar * ci + Ai * cr + Br * pim + bi_ * pre;
                }
            } else if (p == 1) {
                #pragma unroll
                for (int r0i = 0; r0i < 2; ++r0i) {      // pairs (0,2),(1,3)
                    const int i0 = r0i, i1 = r0i + 2;
                    float r0 = re[i0], i0v = im[i0], r1 = re[i1], i1v = im[i1];
                    re[i0] =  ar * r0 - ai * i0v + br * r1 - bi_ * i1v;
                    im[i0] =  ar * i0v + ai * r0 + br * i1v + bi_ * r1;
                    re[i1] = -br * r0 - bi_ * i0v + ar * r1 + ai * i1v;
                    im[i1] = -br * i0v + bi_ * r0 + ar * i1v - ai * r1;
                }
            } else {
                #pragma unroll
                for (int r0i = 0; r0i < 2; ++r0i) {      // pairs (0,1),(2,3)
                    const int i0 = 2 * r0i, i1 = 2 * r0i + 1;
                    float r0 = re[i0], i0v = im[i0], r1 = re[i1], i1v = im[i1];
                    re[i0] =  ar * r0 - ai * i0v + br * r1 - bi_ * i1v;
                    im[i0] =  ar * i0v + ai * r0 + br * i1v + bi_ * r1;
                    re[i1] = -br * r0 - bi_ * i0v + ar * r1 + ai * i1v;
                    im[i1] = -br * i0v + bi_ * r0 + ar * i1v - ai * r1;
                }
            }
        }

        // ---- entangle phases, in-register Ising form
        {
            const float* pb = prm + l * 52 + 24;
            float A = 0.f, B6 = 0.f, B7 = 0.f, T = 0.f;
            int k = 0;
            #pragma unroll
            for (int i = 0; i < 8; ++i) {
                #pragma unroll
                for (int j = i + 1; j < 8; ++j, ++k) {
                    const float th = pb[k];
                    if (j <= 5)      A  += sgnterm(th, lb[5 - i] ^ lb[5 - j]);
                    else if (i == 6) T   = th;                 // pair (6,7)
                    else if (j == 6) B6 += sgnterm(th, lb[5 - i]);
                    else             B7 += sgnterm(th, lb[5 - i]);
                }
            }
            const float AB  = A + B6, AmB = A - B6;
            const float BmT = B7 - T, BpT = B7 + T;
            float ph[4] = { 0.5f * (AB  + BmT), 0.5f * (AB  - BmT),
                            0.5f * (AmB + BpT), 0.5f * (AmB - BpT) };
            #pragma unroll
            for (int r = 0; r < 4; ++r) {
                float c, s;
                __sincosf(ph[r], &s, &c);
                float nr = c * re[r] - s * im[r];
                float ni = c * im[r] + s * re[r];
                re[r] = nr; im[r] = ni;
            }
        }

        // ---- Gray permutation (layer 1 only; layer 2 handled in measurement)
        if (l == 0) {
            float Bre[4], Bim[4];
            #pragma unroll
            for (int m = 0; m < 4; ++m) {
                Bre[m] = shfl_from(re[m], src_lane);
                Bim[m] = shfl_from(im[m], src_lane);
            }
            re[0] = pr ? Bre[3] : Bre[0];  im[0] = pr ? Bim[3] : Bim[0];
            re[1] = pr ? Bre[2] : Bre[1];  im[1] = pr ? Bim[2] : Bim[1];
            re[2] = pr ? Bre[0] : Bre[3];  im[2] = pr ? Bim[0] : Bim[3];
            re[3] = pr ? Bre[1] : Bre[2];  im[3] = pr ? Bim[1] : Bim[2];
        }
    }

    // ---- measurement with Gray-relabeled masks: sign_w = (-1)^{bit_b(Pa)},
    //      bit_b(Pa) = a_b ^ a_{b+1}, b = 7-w.
    float p0 = re[0]*re[0] + im[0]*im[0];
    float p1 = re[1]*re[1] + im[1]*im[1];
    float p2 = re[2]*re[2] + im[2]*im[2];
    float p3 = re[3]*re[3] + im[3]*im[3];
    float psum = p0 + p1 + p2 + p3;

    float v = psum;                       // full signed WHT over lanes
    #pragma unroll
    for (int m = 1; m < 64; m <<= 1) {
        float pp = shfx(v, m);
        v = (lane & m) ? (pp - v) : (v + pp);
    }
    // qubit 6: sign a_1^a_2 ; qubit 7: sign a_0^a_1
    float t6 = p0 + p1 - p2 - p3;  t6 = (lane & 1) ? -t6 : t6;
    float t7 = p0 - p1 - p2 + p3;
    #pragma unroll
    for (int m = 1; m < 64; m <<= 1) { t6 += shfx(t6, m); t7 += shfx(t7, m); }

    const float e0 = shfl_from(v, 32);   // qubit0: mask a7
    const float e1 = shfl_from(v, 48);   // qubit1: a6^a7
    const float e2 = shfl_from(v, 24);   // qubit2: a5^a6
    const float e3 = shfl_from(v, 12);   // qubit3: a4^a5
    const float e4 = shfl_from(v, 6);    // qubit4: a3^a4
    const float e5 = shfl_from(v, 3);    // qubit5: a2^a3

    // ---- linear head
    if (lane < 10) {
        const float* Wr = W + lane * 8;
        float acc = bvec[lane];
        acc += e0 * Wr[0] + e1 * Wr[1] + e2 * Wr[2] + e3 * Wr[3];
        acc += e4 * Wr[4] + e5 * Wr[5] + t6 * Wr[6] + t7 * Wr[7];
        out[bi * 10 + lane] = acc;
    }
}

extern "C" void kernel_launch(void* const* d_in, const int* in_sizes, int n_in,
                              void* d_out, int out_size, void* d_ws, size_t ws_size,
                              hipStream_t stream) {
    const float* x    = (const float*)d_in[0];   // [4096,8]
    const float* prm  = (const float*)d_in[1];   // [104]
    const float* W    = (const float*)d_in[2];   // [10,8]
    const float* bvec = (const float*)d_in[3];   // [10]
    float* out = (float*)d_out;                  // [4096,10]

    const int B = in_sizes[0] / 8;               // 4096
    vqc_fused<<<B / 4, 256, 0, stream>>>(x, prm, W, bvec, out);
}

// Round 4
// 14.165 us; speedup vs baseline: 2.1920x; 1.0018x over previous
//
#include <hip/hip_runtime.h>

// VQC 8 qubits / 2 layers / B=4096 — one fused kernel, TWO batch elems per wave.
// Amplitude a = (lane<<2)|r ; qubit q <-> bit (7-q); bits>=2 are lane bits.
// Complex amp stored as v2f (re,im); gate math uses packed dual-f32 VOP3P
// (v_pk_mul_f32 / v_pk_fma_f32 with op_sel half-swizzles) — 4 pk-FMA per amp
// per gate instead of 8 scalar ops.
// Entangle block per layer = diagonal phase (in-register Ising form) x Gray
// permutation a->a^(a>>1); layer-2 permutation folded into measurement masks.

typedef float v2f __attribute__((ext_vector_type(2)));

#define PI_HALF 1.57079632679489662f

__device__ __forceinline__ float shfx(float v, int m)      { return __shfl_xor(v, m, 64); }
__device__ __forceinline__ float shfl_from(float v, int l) { return __shfl(v, l, 64); }
__device__ __forceinline__ v2f shfx2(v2f z, int m) {
    v2f r; r.x = shfx(z.x, m); r.y = shfx(z.y, m); return r;
}
__device__ __forceinline__ v2f shfl_from2(v2f z, int l) {
    v2f r; r.x = shfl_from(z.x, l); r.y = shfl_from(z.y, l); return r;
}
__device__ __forceinline__ float rdlane(float v, int l) {
    return __int_as_float(__builtin_amdgcn_readlane(__float_as_int(v), l));
}
// +th if (pword&1)==1 else -th
__device__ __forceinline__ float sgnterm(float th, int pword) {
    return __int_as_float(__float_as_int(-th) ^ (int)((unsigned)pword << 31));
}

// ---- packed dual-f32 helpers ----
__device__ __forceinline__ v2f pk_mul(v2f a, v2f b) {
    v2f d; asm("v_pk_mul_f32 %0, %1, %2" : "=v"(d) : "v"(a), "v"(b)); return d;
}
__device__ __forceinline__ v2f pk_fma(v2f a, v2f b, v2f c) {
    v2f d; asm("v_pk_fma_f32 %0, %1, %2, %3" : "=v"(d) : "v"(a), "v"(b), "v"(c)); return d;
}
// src1 halves swapped: (a.lo*b.hi + c.lo , a.hi*b.lo + c.hi)
__device__ __forceinline__ v2f pk_fma_sw1(v2f a, v2f b, v2f c) {
    v2f d; asm("v_pk_fma_f32 %0, %1, %2, %3 op_sel:[0,1,0] op_sel_hi:[1,0,1]"
               : "=v"(d) : "v"(a), "v"(b), "v"(c)); return d;
}
// src0 AND src1 swapped: (a.hi*b.hi + c.lo , a.lo*b.lo + c.hi)
__device__ __forceinline__ v2f pk_fma_sw01(v2f a, v2f b, v2f c) {
    v2f d; asm("v_pk_fma_f32 %0, %1, %2, %3 op_sel:[1,1,0] op_sel_hi:[0,0,1]"
               : "=v"(d) : "v"(a), "v"(b), "v"(c)); return d;
}

__global__ __launch_bounds__(256) void vqc_fused(
    const float* __restrict__ x,      // [4096,8]
    const float* __restrict__ prm,    // [104]
    const float* __restrict__ W,      // [10,8]
    const float* __restrict__ bvec,   // [10]
    float* __restrict__ out)          // [4096,10]
{
    const int lane = threadIdx.x & 63;
    const int wid  = __builtin_amdgcn_readfirstlane((int)(threadIdx.x >> 6));
    const int bi0  = (blockIdx.x << 3) + (wid << 1);
    const int bi1  = bi0 + 1;

    // ---- distributed fused-rotation matrices: lane t in [0,16) owns (l=t>>3,q=t&7)
    float mar, mai, mbr, mbi;
    {
        const int t = lane & 15;
        const int l = t >> 3, q = t & 7;
        const float* p3 = prm + l * 52 + 3 * q;
        float cx, sx, cy, sy, cz, sz;
        __sincosf(p3[0] * 0.5f, &sx, &cx);
        __sincosf(p3[1] * 0.5f, &sy, &cy);
        __sincosf(p3[2] * 0.5f, &sz, &cz);
        float n00r =  cy * cx, n00i =  sy * sx;
        float n01r = -sy * cx, n01i = -cy * sx;
        mar = cz * n00r + sz * n00i;
        mai = cz * n00i - sz * n00r;
        mbr = cz * n01r + sz * n01i;
        mbi = cz * n01i - sz * n01r;
    }

    // ---- initial product states: RY(x_w*pi)|0..0> for both elems
    const float4 xa0 = ((const float4*)(x + bi0 * 8))[0];
    const float4 xa1 = ((const float4*)(x + bi0 * 8))[1];
    const float4 xb0 = ((const float4*)(x + bi1 * 8))[0];
    const float4 xb1 = ((const float4*)(x + bi1 * 8))[1];
    const float xs[2][8] = {{xa0.x, xa0.y, xa0.z, xa0.w, xa1.x, xa1.y, xa1.z, xa1.w},
                            {xb0.x, xb0.y, xb0.z, xb0.w, xb1.x, xb1.y, xb1.z, xb1.w}};
    v2f z[2][4];
    #pragma unroll
    for (int e = 0; e < 2; ++e) {
        float cwv[8], swv[8];
        #pragma unroll
        for (int w = 0; w < 8; ++w)
            __sincosf(xs[e][w] * PI_HALF, &swv[w], &cwv[w]);
        float base = 1.f;
        #pragma unroll
        for (int w = 0; w < 6; ++w)
            base *= ((lane >> (5 - w)) & 1) ? swv[w] : cwv[w];
        z[e][0] = v2f{base * cwv[6] * cwv[7], 0.f};
        z[e][1] = v2f{base * cwv[6] * swv[7], 0.f};
        z[e][2] = v2f{base * swv[6] * cwv[7], 0.f};
        z[e][3] = v2f{base * swv[6] * swv[7], 0.f};
    }

    // ---- per-lane bit words for phase signs
    int lb[6];
    #pragma unroll
    for (int b = 0; b < 6; ++b) lb[b] = lane >> b;

    // ---- Gray permutation constants (layer 1 only)
    const int pr = __popc(lane) & 1;
    int g = lane; g ^= g >> 1; g ^= g >> 2; g ^= g >> 4;
    const int src_lane = g;

    #pragma unroll
    for (int l = 0; l < 2; ++l) {
        // ---- 8 fused rotations (qubit i -> amplitude bit p = 7-i)
        #pragma unroll
        for (int i = 0; i < 8; ++i) {
            const int srcl = l * 8 + i;
            const float ar  = rdlane(mar, srcl);
            const float ai  = rdlane(mai, srcl);
            const float br  = rdlane(mbr, srcl);
            const float bi_ = rdlane(mbi, srcl);
            const int p = 7 - i;
            if (p >= 2) {
                const int mk = 1 << (p - 2);
                const int h  = (lane >> (p - 2)) & 1;
                const float Ai = h ? -ai : ai;
                const float Br = h ? -br : br;
                const v2f P1 = {ar, ar};
                const v2f P2 = {-Ai, Ai};
                const v2f P3 = {Br, Br};
                const v2f P4 = {-bi_, bi_};
                #pragma unroll
                for (int e = 0; e < 2; ++e) {
                    #pragma unroll
                    for (int r = 0; r < 4; ++r) {
                        v2f zz = z[e][r];
                        v2f pz = shfx2(zz, mk);
                        v2f t = pk_mul(P1, zz);       // (ar*re, ar*im)
                        t = pk_fma_sw1(P2, zz, t);    // (-Ai*im, Ai*re)
                        t = pk_fma(P3, pz, t);        // (Br*pre, Br*pim)
                        t = pk_fma_sw1(P4, pz, t);    // (-bi*pim, bi*pre)
                        z[e][r] = t;
                    }
                }
            } else {
                const v2f P1 = {ar, ar};
                const v2f P2 = {-ai, ai};
                const v2f P3 = {br, br};
                const v2f P4 = {-bi_, bi_};
                const v2f Q1 = {-br, -br};
                const int i0a = (p == 1) ? 0 : 0, i1a = (p == 1) ? 2 : 1;
                const int i0b = (p == 1) ? 1 : 2, i1b = (p == 1) ? 3 : 3;
                #pragma unroll
                for (int e = 0; e < 2; ++e) {
                    {
                        v2f z0 = z[e][i0a], z1 = z[e][i1a];
                        v2f t0 = pk_mul(P1, z0); t0 = pk_fma_sw1(P2, z0, t0);
                        t0 = pk_fma(P3, z1, t0); t0 = pk_fma_sw1(P4, z1, t0);
                        v2f t1 = pk_mul(Q1, z0); t1 = pk_fma_sw1(P4, z0, t1);
                        t1 = pk_fma(P1, z1, t1); t1 = pk_fma_sw01(P2, z1, t1);
                        z[e][i0a] = t0; z[e][i1a] = t1;
                    }
                    {
                        v2f z0 = z[e][i0b], z1 = z[e][i1b];
                        v2f t0 = pk_mul(P1, z0); t0 = pk_fma_sw1(P2, z0, t0);
                        t0 = pk_fma(P3, z1, t0); t0 = pk_fma_sw1(P4, z1, t0);
                        v2f t1 = pk_mul(Q1, z0); t1 = pk_fma_sw1(P4, z0, t1);
                        t1 = pk_fma(P1, z1, t1); t1 = pk_fma_sw01(P2, z1, t1);
                        z[e][i0b] = t0; z[e][i1b] = t1;
                    }
                }
            }
        }

        // ---- entangle phases, in-register Ising form (shared across elems)
        {
            const float* pb = prm + l * 52 + 24;
            float A = 0.f, B6 = 0.f, B7 = 0.f, T = 0.f;
            int k = 0;
            #pragma unroll
            for (int i = 0; i < 8; ++i) {
                #pragma unroll
                for (int j = i + 1; j < 8; ++j, ++k) {
                    const float th = pb[k];
                    if (j <= 5)      A  += sgnterm(th, lb[5 - i] ^ lb[5 - j]);
                    else if (i == 6) T   = th;                 // pair (6,7)
                    else if (j == 6) B6 += sgnterm(th, lb[5 - i]);
                    else             B7 += sgnterm(th, lb[5 - i]);
                }
            }
            const float AB  = A + B6, AmB = A - B6;
            const float BmT = B7 - T, BpT = B7 + T;
            const float ph[4] = { 0.5f * (AB  + BmT), 0.5f * (AB  - BmT),
                                  0.5f * (AmB + BpT), 0.5f * (AmB - BpT) };
            #pragma unroll
            for (int r = 0; r < 4; ++r) {
                float c, s;
                __sincosf(ph[r], &s, &c);
                const v2f Cc = {c, c};
                const v2f Cs = {-s, s};
                #pragma unroll
                for (int e = 0; e < 2; ++e) {
                    v2f t = pk_mul(Cc, z[e][r]);
                    z[e][r] = pk_fma_sw1(Cs, z[e][r], t);
                }
            }
        }

        // ---- Gray permutation (layer 1 only; layer 2 folded into measurement)
        if (l == 0) {
            #pragma unroll
            for (int e = 0; e < 2; ++e) {
                v2f B0 = shfl_from2(z[e][0], src_lane);
                v2f B1 = shfl_from2(z[e][1], src_lane);
                v2f B2 = shfl_from2(z[e][2], src_lane);
                v2f B3 = shfl_from2(z[e][3], src_lane);
                z[e][0] = v2f{pr ? B3.x : B0.x, pr ? B3.y : B0.y};
                z[e][1] = v2f{pr ? B2.x : B1.x, pr ? B2.y : B1.y};
                z[e][2] = v2f{pr ? B0.x : B3.x, pr ? B0.y : B3.y};
                z[e][3] = v2f{pr ? B1.x : B2.x, pr ? B1.y : B2.y};
            }
        }
    }

    // ---- measurement (Gray-relabeled masks), both elems packed in v2f
    float vA, vB, t6A, t6B, t7A, t7B;
    #pragma unroll
    for (int e = 0; e < 2; ++e) {
        float p0 = z[e][0].x*z[e][0].x + z[e][0].y*z[e][0].y;
        float p1 = z[e][1].x*z[e][1].x + z[e][1].y*z[e][1].y;
        float p2 = z[e][2].x*z[e][2].x + z[e][2].y*z[e][2].y;
        float p3 = z[e][3].x*z[e][3].x + z[e][3].y*z[e][3].y;
        float ps = p0 + p1 + p2 + p3;
        float t6 = p0 + p1 - p2 - p3;  t6 = (lane & 1) ? -t6 : t6;
        float t7 = p0 - p1 - p2 + p3;
        if (e == 0) { vA = ps; t6A = t6; t7A = t7; }
        else        { vB = ps; t6B = t6; t7B = t7; }
    }
    v2f vv  = {vA, vB};
    v2f t6v = {t6A, t6B};
    v2f t7v = {t7A, t7B};
    #pragma unroll
    for (int m = 1; m < 64; m <<= 1) {
        v2f pp = shfx2(vv, m);
        const bool neg = lane & m;
        vv.x = neg ? (pp.x - vv.x) : (vv.x + pp.x);
        vv.y = neg ? (pp.y - vv.y) : (vv.y + pp.y);
        t6v += shfx2(t6v, m);
        t7v += shfx2(t7v, m);
    }
    const float e0A = shfl_from(vv.x, 32), e0B = shfl_from(vv.y, 32);
    const float e1A = shfl_from(vv.x, 48), e1B = shfl_from(vv.y, 48);
    const float e2A = shfl_from(vv.x, 24), e2B = shfl_from(vv.y, 24);
    const float e3A = shfl_from(vv.x, 12), e3B = shfl_from(vv.y, 12);
    const float e4A = shfl_from(vv.x,  6), e4B = shfl_from(vv.y,  6);
    const float e5A = shfl_from(vv.x,  3), e5B = shfl_from(vv.y,  3);

    // ---- linear head: lanes 0..9 store both elems
    if (lane < 10) {
        const float* Wr = W + lane * 8;
        const float w0 = Wr[0], w1 = Wr[1], w2 = Wr[2], w3 = Wr[3];
        const float w4 = Wr[4], w5 = Wr[5], w6 = Wr[6], w7 = Wr[7];
        const float bv = bvec[lane];
        float accA = bv + e0A*w0 + e1A*w1 + e2A*w2 + e3A*w3
                        + e4A*w4 + e5A*w5 + t6v.x*w6 + t7v.x*w7;
        float accB = bv + e0B*w0 + e1B*w1 + e2B*w2 + e3B*w3
                        + e4B*w4 + e5B*w5 + t6v.y*w6 + t7v.y*w7;
        out[bi0 * 10 + lane] = accA;
        out[bi1 * 10 + lane] = accB;
    }
}

extern "C" void kernel_launch(void* const* d_in, const int* in_sizes, int n_in,
                              void* d_out, int out_size, void* d_ws, size_t ws_size,
                              hipStream_t stream) {
    const float* x    = (const float*)d_in[0];   // [4096,8]
    const float* prm  = (const float*)d_in[1];   // [104]
    const float* W    = (const float*)d_in[2];   // [10,8]
    const float* bvec = (const float*)d_in[3];   // [10]
    float* out = (float*)d_out;                  // [4096,10]

    const int B = in_sizes[0] / 8;               // 4096
    vqc_fused<<<B / 8, 256, 0, stream>>>(x, prm, W, bvec, out);
}